// Round 5
// baseline (2078.097 us; speedup 1.0000x reference)
//
#include <hip/hip_runtime.h>

#define NBATCH 256
#define SLEN   2048
#define NTAG   64
#define BOS_T  1
#define EOS_T  2

// bt: (S-1) rows x 64 bytes = 131008 -> 131072 ; only LDS user now
#define BT_BYTES 131072
#define LDS_BYTES BT_BYTES

typedef float f32x4 __attribute__((ext_vector_type(4)));

// broadcast lane `lane`'s value of v to all lanes (compile-time lane -> v_readlane)
__device__ __forceinline__ float lane_bcast(float v, int lane) {
    return __uint_as_float(__builtin_amdgcn_readlane(__float_as_uint(v), lane));
}

__global__ __launch_bounds__(64, 1)
void crf_viterbi(const float* __restrict__ emissions,  // [B,S,C]
                 const float* __restrict__ mask,       // [B,S]
                 const float* __restrict__ trans,      // [C,C]
                 int* __restrict__ out)                // [B,S] int32 tags
{
    extern __shared__ unsigned char lds[];
    unsigned char* bt = lds;                       // [S-1][64] backpointers

    const int b = blockIdx.x;
    const int c = threadIdx.x;                     // current tag, 0..63

    // T column c: tc4[q][k] = T[4q+k][c]
    f32x4 tc4[16];
    #pragma unroll
    for (int q = 0; q < 16; ++q) {
        tc4[q][0] = trans[(q * 4 + 0) * NTAG + c];
        tc4[q][1] = trans[(q * 4 + 1) * NTAG + c];
        tc4[q][2] = trans[(q * 4 + 2) * NTAG + c];
        tc4[q][3] = trans[(q * 4 + 3) * NTAG + c];
    }

    // length = sum(mask[b,:]) ; mask is left-contiguous 1s
    const float* mrow = mask + (size_t)b * SLEN;
    float msum = 0.f;
    #pragma unroll
    for (int k = 0; k < SLEN / 64; ++k) msum += mrow[c + k * 64];
    #pragma unroll
    for (int off = 32; off >= 1; off >>= 1) msum += __shfl_xor(msum, off, 64);
    const int len = (int)msum;                     // in [1024, 2048]

    const float* E = emissions + (size_t)b * SLEN * NTAG;

    // alpha0 = emissions[:,0] + T[BOS,:]  (alpha[c] lives in lane c's register)
    float a = E[c] + tc4[BOS_T / 4][BOS_T % 4];

    // depth-2 emissions prefetch; no barriers/fences anywhere in the loop,
    // so these stay in flight across iterations.
    float e0 = E[1 * NTAG + c];
    float e1 = E[((2 < len) ? 2 : (len - 1)) * NTAG + c];

    for (int t = 1; t < len; ++t) {
        // pin the T column in VGPRs: opaque asm write each iteration makes
        // rematerialization-from-global illegal -> loop-carried registers
        #pragma unroll
        for (int q = 0; q < 16; ++q) asm volatile("" : "+v"(tc4[q]));

        float emit = e0;
        e0 = e1;
        int tn = (t + 2 < len) ? (t + 2) : (len - 1);
        e1 = E[tn * NTAG + c];

        // 4 independent chains over contiguous prev ranges [16j, 16j+16),
        // candidates via register broadcast (no LDS)
        float bestv[4];
        int   besti[4];
        #pragma unroll
        for (int j = 0; j < 4; ++j) {
            float bv = -3.402823466e38f;
            int   bi = 0;
            #pragma unroll
            for (int k = 0; k < 16; ++k) {
                const int p = j * 16 + k;
                float cand = lane_bcast(a, p) + tc4[p >> 2][p & 3];
                if (cand > bv) { bv = cand; bi = p; }
            }
            bestv[j] = bv; besti[j] = bi;
        }
        // merge in ascending-prev order, strict > keeps first argmax
        float bv = bestv[0]; int bi = besti[0];
        if (bestv[1] > bv) { bv = bestv[1]; bi = besti[1]; }
        if (bestv[2] > bv) { bv = bestv[2]; bi = besti[2]; }
        if (bestv[3] > bv) { bv = bestv[3]; bi = besti[3]; }

        bt[(t - 1) * NTAG + c] = (unsigned char)bi;   // fire-and-forget ds_write
        a = bv + emit;                                // alpha update in-register
    }

    // final scores: alpha + T[:,EOS]
    float fin = a + trans[c * NTAG + EOS_T];

    // wave argmax: value desc, index asc (first occurrence)
    float v = fin; int idx = c;
    #pragma unroll
    for (int off = 1; off < 64; off <<= 1) {
        float ov = __shfl_xor(v, off, 64);
        int   oi = __shfl_xor(idx, off, 64);
        if (ov > v || (ov == v && oi < idx)) { v = ov; idx = oi; }
    }
    int cur = idx;                                  // best_last (wave-uniform)

    int* orow = out + (size_t)b * SLEN;
    for (int t = len + c; t < SLEN; t += 64) orow[t] = 0;   // PAD tail
    if (c == 0) orow[len - 1] = cur;

    // drain bt ds_writes once, then chase backpointers (uniform -> broadcast)
    asm volatile("s_waitcnt lgkmcnt(0)" ::: "memory");
    for (int t = len - 2; t >= 0; --t) {
        cur = bt[t * NTAG + cur];
        if (c == 0) orow[t] = cur;
    }
}

extern "C" void kernel_launch(void* const* d_in, const int* in_sizes, int n_in,
                              void* d_out, int out_size, void* d_ws, size_t ws_size,
                              hipStream_t stream) {
    const float* emissions = (const float*)d_in[0];
    const float* mask      = (const float*)d_in[1];
    const float* trans     = (const float*)d_in[2];
    int* out = (int*)d_out;

    (void)hipFuncSetAttribute((const void*)crf_viterbi,
                              hipFuncAttributeMaxDynamicSharedMemorySize,
                              LDS_BYTES);

    crf_viterbi<<<NBATCH, 64, LDS_BYTES, stream>>>(emissions, mask, trans, out);
}

// Round 6
// 1464.074 us; speedup vs baseline: 1.4194x; 1.4194x over previous
//
#include <hip/hip_runtime.h>

#define NBATCH 256
#define SLEN   2048
#define NTAG   64
#define BOS_T  1
#define EOS_T  2

// bt: (S-1) rows x 64 bytes = 131008 -> 131072 ; only LDS user
#define BT_BYTES 131072
#define LDS_BYTES BT_BYTES

// broadcast lane `lane`'s value of v to all lanes (literal lane -> v_readlane)
__device__ __forceinline__ float lane_bcast(float v, int lane) {
    return __uint_as_float(__builtin_amdgcn_readlane(__float_as_uint(v), lane));
}

// X-macro over tag ids 0..63
#define TAGS_ALL(X) \
  X(0)  X(1)  X(2)  X(3)  X(4)  X(5)  X(6)  X(7)  \
  X(8)  X(9)  X(10) X(11) X(12) X(13) X(14) X(15) \
  X(16) X(17) X(18) X(19) X(20) X(21) X(22) X(23) \
  X(24) X(25) X(26) X(27) X(28) X(29) X(30) X(31) \
  X(32) X(33) X(34) X(35) X(36) X(37) X(38) X(39) \
  X(40) X(41) X(42) X(43) X(44) X(45) X(46) X(47) \
  X(48) X(49) X(50) X(51) X(52) X(53) X(54) X(55) \
  X(56) X(57) X(58) X(59) X(60) X(61) X(62) X(63)

#define DECL_TC(p) float tc##p = trans[(p) * NTAG + c];
#define KEEP_TC(p) asm volatile("" : "+v"(tc##p));

// tournament leaf: candidates pa<pb; >= keeps the lower index on ties
#define LEAF(i, pa, pb) \
  float va##i; int ia##i; { \
    float ca_ = lane_bcast(a, pa) + tc##pa; \
    float cb_ = lane_bcast(a, pb) + tc##pb; \
    bool g_ = (ca_ >= cb_); \
    va##i = g_ ? ca_ : cb_; ia##i = g_ ? (pa) : (pb); }

// internal node: left subtree holds lower indices; >= keeps left on ties
#define MRG(vo, io, vA, iA, vB, iB) \
  float vo; int io; { bool g_ = ((vA) >= (vB)); \
    vo = g_ ? (vA) : (vB); io = g_ ? (iA) : (iB); }

__global__ __launch_bounds__(64, 1)
void crf_viterbi(const float* __restrict__ emissions,  // [B,S,C]
                 const float* __restrict__ mask,       // [B,S]
                 const float* __restrict__ trans,      // [C,C]
                 int* __restrict__ out)                // [B,S] int32 tags
{
    extern __shared__ unsigned char lds[];
    unsigned char* bt = lds;                       // [S-1][64] backpointers

    const int b = blockIdx.x;
    const int c = threadIdx.x;                     // current tag, 0..63

    // T column c in 64 NAMED scalars (no arrays -> nothing can go to scratch)
    TAGS_ALL(DECL_TC)

    // length = sum(mask[b,:]) ; mask is left-contiguous 1s
    const float* mrow = mask + (size_t)b * SLEN;
    float msum = 0.f;
    #pragma unroll
    for (int k = 0; k < SLEN / 64; ++k) msum += mrow[c + k * 64];
    #pragma unroll
    for (int off = 32; off >= 1; off >>= 1) msum += __shfl_xor(msum, off, 64);
    const int len = (int)msum;                     // in [1024, 2048]

    const float* E = emissions + (size_t)b * SLEN * NTAG;

    // alpha0 = emissions[:,0] + T[BOS,:]  (alpha[c] lives in lane c's register)
    float a = E[c] + tc1;

    // depth-2 emissions prefetch; no fences/barriers in the loop keep them in flight
    float e0 = E[1 * NTAG + c];
    float e1 = E[((2 < len) ? 2 : (len - 1)) * NTAG + c];

    for (int t = 1; t < len; ++t) {
        // per-iteration opaque redefinition: loop-carried VGPRs, remat illegal
        TAGS_ALL(KEEP_TC)

        float emit = e0;
        e0 = e1;
        int tn = (t + 2 < len) ? (t + 2) : (len - 1);
        e1 = E[tn * NTAG + c];

        // 64-candidate tournament, fully expanded, exact first-occurrence argmax
        LEAF(0,  0,  1)  LEAF(1,  2,  3)  LEAF(2,  4,  5)  LEAF(3,  6,  7)
        LEAF(4,  8,  9)  LEAF(5,  10, 11) LEAF(6,  12, 13) LEAF(7,  14, 15)
        LEAF(8,  16, 17) LEAF(9,  18, 19) LEAF(10, 20, 21) LEAF(11, 22, 23)
        LEAF(12, 24, 25) LEAF(13, 26, 27) LEAF(14, 28, 29) LEAF(15, 30, 31)
        LEAF(16, 32, 33) LEAF(17, 34, 35) LEAF(18, 36, 37) LEAF(19, 38, 39)
        LEAF(20, 40, 41) LEAF(21, 42, 43) LEAF(22, 44, 45) LEAF(23, 46, 47)
        LEAF(24, 48, 49) LEAF(25, 50, 51) LEAF(26, 52, 53) LEAF(27, 54, 55)
        LEAF(28, 56, 57) LEAF(29, 58, 59) LEAF(30, 60, 61) LEAF(31, 62, 63)

        MRG(vb0,  ib0,  va0,  ia0,  va1,  ia1)   MRG(vb1,  ib1,  va2,  ia2,  va3,  ia3)
        MRG(vb2,  ib2,  va4,  ia4,  va5,  ia5)   MRG(vb3,  ib3,  va6,  ia6,  va7,  ia7)
        MRG(vb4,  ib4,  va8,  ia8,  va9,  ia9)   MRG(vb5,  ib5,  va10, ia10, va11, ia11)
        MRG(vb6,  ib6,  va12, ia12, va13, ia13)  MRG(vb7,  ib7,  va14, ia14, va15, ia15)
        MRG(vb8,  ib8,  va16, ia16, va17, ia17)  MRG(vb9,  ib9,  va18, ia18, va19, ia19)
        MRG(vb10, ib10, va20, ia20, va21, ia21)  MRG(vb11, ib11, va22, ia22, va23, ia23)
        MRG(vb12, ib12, va24, ia24, va25, ia25)  MRG(vb13, ib13, va26, ia26, va27, ia27)
        MRG(vb14, ib14, va28, ia28, va29, ia29)  MRG(vb15, ib15, va30, ia30, va31, ia31)

        MRG(vc0, ic0, vb0,  ib0,  vb1,  ib1)     MRG(vc1, ic1, vb2,  ib2,  vb3,  ib3)
        MRG(vc2, ic2, vb4,  ib4,  vb5,  ib5)     MRG(vc3, ic3, vb6,  ib6,  vb7,  ib7)
        MRG(vc4, ic4, vb8,  ib8,  vb9,  ib9)     MRG(vc5, ic5, vb10, ib10, vb11, ib11)
        MRG(vc6, ic6, vb12, ib12, vb13, ib13)    MRG(vc7, ic7, vb14, ib14, vb15, ib15)

        MRG(vd0, id0, vc0, ic0, vc1, ic1)        MRG(vd1, id1, vc2, ic2, vc3, ic3)
        MRG(vd2, id2, vc4, ic4, vc5, ic5)        MRG(vd3, id3, vc6, ic6, vc7, ic7)

        MRG(ve0, ie0, vd0, id0, vd1, id1)        MRG(ve1, ie1, vd2, id2, vd3, id3)

        MRG(vf0, if0, ve0, ie0, ve1, ie1)

        bt[(t - 1) * NTAG + c] = (unsigned char)if0;  // fire-and-forget ds_write
        a = vf0 + emit;                               // alpha update in-register
    }

    // final scores: alpha + T[:,EOS]
    float fin = a + trans[c * NTAG + EOS_T];

    // wave argmax: value desc, index asc (first occurrence)
    float v = fin; int idx = c;
    #pragma unroll
    for (int off = 1; off < 64; off <<= 1) {
        float ov = __shfl_xor(v, off, 64);
        int   oi = __shfl_xor(idx, off, 64);
        if (ov > v || (ov == v && oi < idx)) { v = ov; idx = oi; }
    }
    int cur = idx;                                  // best_last (wave-uniform)

    int* orow = out + (size_t)b * SLEN;
    for (int t = len + c; t < SLEN; t += 64) orow[t] = 0;   // PAD tail
    if (c == 0) orow[len - 1] = cur;

    // drain bt ds_writes once, then chase backpointers (uniform -> broadcast)
    asm volatile("s_waitcnt lgkmcnt(0)" ::: "memory");
    for (int t = len - 2; t >= 0; --t) {
        cur = bt[t * NTAG + cur];
        if (c == 0) orow[t] = cur;
    }
}

extern "C" void kernel_launch(void* const* d_in, const int* in_sizes, int n_in,
                              void* d_out, int out_size, void* d_ws, size_t ws_size,
                              hipStream_t stream) {
    const float* emissions = (const float*)d_in[0];
    const float* mask      = (const float*)d_in[1];
    const float* trans     = (const float*)d_in[2];
    int* out = (int*)d_out;

    (void)hipFuncSetAttribute((const void*)crf_viterbi,
                              hipFuncAttributeMaxDynamicSharedMemorySize,
                              LDS_BYTES);

    crf_viterbi<<<NBATCH, 64, LDS_BYTES, stream>>>(emissions, mask, trans, out);
}

// Round 7
// 1317.162 us; speedup vs baseline: 1.5777x; 1.1115x over previous
//
#include <hip/hip_runtime.h>

#define NBATCH 256
#define SLEN   2048
#define NTAG   64
#define BOS_T  1
#define EOS_T  2

// bt: (S-1) rows x 64 bytes = 131008 -> 131072 ; only LDS user
#define BT_BYTES 131072
#define LDS_BYTES BT_BYTES

// broadcast lane `lane`'s value of v to all lanes (literal lane -> v_readlane)
__device__ __forceinline__ float lane_bcast(float v, int lane) {
    return __uint_as_float(__builtin_amdgcn_readlane(__float_as_uint(v), lane));
}

// X-macro over tag ids 0..63
#define TAGS_ALL(X) \
  X(0)  X(1)  X(2)  X(3)  X(4)  X(5)  X(6)  X(7)  \
  X(8)  X(9)  X(10) X(11) X(12) X(13) X(14) X(15) \
  X(16) X(17) X(18) X(19) X(20) X(21) X(22) X(23) \
  X(24) X(25) X(26) X(27) X(28) X(29) X(30) X(31) \
  X(32) X(33) X(34) X(35) X(36) X(37) X(38) X(39) \
  X(40) X(41) X(42) X(43) X(44) X(45) X(46) X(47) \
  X(48) X(49) X(50) X(51) X(52) X(53) X(54) X(55) \
  X(56) X(57) X(58) X(59) X(60) X(61) X(62) X(63)

#define DECL_TC(p) float tc##p = trans[(p) * NTAG + c];
#define KEEP_TC(p) asm volatile("" : "+v"(tc##p));

// tournament leaf: candidates pa<pb; >= keeps the lower index on ties
#define LEAF(i, pa, pb) \
  float va##i; int ia##i; { \
    float ca_ = lane_bcast(a, pa) + tc##pa; \
    float cb_ = lane_bcast(a, pb) + tc##pb; \
    bool g_ = (ca_ >= cb_); \
    va##i = g_ ? ca_ : cb_; ia##i = g_ ? (pa) : (pb); }

// internal node: left subtree holds lower indices; >= keeps left on ties
#define MRG(vo, io, vA, iA, vB, iB) \
  float vo; int io; { bool g_ = ((vA) >= (vB)); \
    vo = g_ ? (vA) : (vB); io = g_ ? (iA) : (iB); }

// waves_per_eu(1,1): the dynamic-LDS footprint (131KB) limits us to 1 wg/CU at
// runtime, but the compiler can't see extern-shared size and otherwise targets
// 8 waves/EU, capping VGPRs at ~56 and spilling the T-column (rounds 2-6).
// Telling it min=max=1 hands regalloc the full register budget.
__global__ __launch_bounds__(64)
__attribute__((amdgpu_waves_per_eu(1, 1)))
void crf_viterbi(const float* __restrict__ emissions,  // [B,S,C]
                 const float* __restrict__ mask,       // [B,S]
                 const float* __restrict__ trans,      // [C,C]
                 int* __restrict__ out)                // [B,S] int32 tags
{
    extern __shared__ unsigned char lds[];
    unsigned char* bt = lds;                       // [S-1][64] backpointers

    const int b = blockIdx.x;
    const int c = threadIdx.x;                     // current tag, 0..63

    // T column c in 64 NAMED scalars (no arrays -> nothing can go to alloca)
    TAGS_ALL(DECL_TC)

    // length = sum(mask[b,:]) ; mask is left-contiguous 1s
    const float* mrow = mask + (size_t)b * SLEN;
    float msum = 0.f;
    #pragma unroll
    for (int k = 0; k < SLEN / 64; ++k) msum += mrow[c + k * 64];
    #pragma unroll
    for (int off = 32; off >= 1; off >>= 1) msum += __shfl_xor(msum, off, 64);
    const int len = (int)msum;                     // in [1024, 2048]

    const float* E = emissions + (size_t)b * SLEN * NTAG;

    // alpha0 = emissions[:,0] + T[BOS,:]  (alpha[c] lives in lane c's register)
    float a = E[c] + tc1;

    // depth-2 emissions prefetch; no fences/barriers in the loop keep them in flight
    float e0 = E[1 * NTAG + c];
    float e1 = E[((2 < len) ? 2 : (len - 1)) * NTAG + c];

    for (int t = 1; t < len; ++t) {
        // per-iteration opaque redefinition: loop-carried VGPRs, remat illegal
        TAGS_ALL(KEEP_TC)

        float emit = e0;
        e0 = e1;
        int tn = (t + 2 < len) ? (t + 2) : (len - 1);
        e1 = E[tn * NTAG + c];

        // 64-candidate tournament, fully expanded, exact first-occurrence argmax
        LEAF(0,  0,  1)  LEAF(1,  2,  3)  LEAF(2,  4,  5)  LEAF(3,  6,  7)
        LEAF(4,  8,  9)  LEAF(5,  10, 11) LEAF(6,  12, 13) LEAF(7,  14, 15)
        LEAF(8,  16, 17) LEAF(9,  18, 19) LEAF(10, 20, 21) LEAF(11, 22, 23)
        LEAF(12, 24, 25) LEAF(13, 26, 27) LEAF(14, 28, 29) LEAF(15, 30, 31)
        LEAF(16, 32, 33) LEAF(17, 34, 35) LEAF(18, 36, 37) LEAF(19, 38, 39)
        LEAF(20, 40, 41) LEAF(21, 42, 43) LEAF(22, 44, 45) LEAF(23, 46, 47)
        LEAF(24, 48, 49) LEAF(25, 50, 51) LEAF(26, 52, 53) LEAF(27, 54, 55)
        LEAF(28, 56, 57) LEAF(29, 58, 59) LEAF(30, 60, 61) LEAF(31, 62, 63)

        MRG(vb0,  ib0,  va0,  ia0,  va1,  ia1)   MRG(vb1,  ib1,  va2,  ia2,  va3,  ia3)
        MRG(vb2,  ib2,  va4,  ia4,  va5,  ia5)   MRG(vb3,  ib3,  va6,  ia6,  va7,  ia7)
        MRG(vb4,  ib4,  va8,  ia8,  va9,  ia9)   MRG(vb5,  ib5,  va10, ia10, va11, ia11)
        MRG(vb6,  ib6,  va12, ia12, va13, ia13)  MRG(vb7,  ib7,  va14, ia14, va15, ia15)
        MRG(vb8,  ib8,  va16, ia16, va17, ia17)  MRG(vb9,  ib9,  va18, ia18, va19, ia19)
        MRG(vb10, ib10, va20, ia20, va21, ia21)  MRG(vb11, ib11, va22, ia22, va23, ia23)
        MRG(vb12, ib12, va24, ia24, va25, ia25)  MRG(vb13, ib13, va26, ia26, va27, ia27)
        MRG(vb14, ib14, va28, ia28, va29, ia29)  MRG(vb15, ib15, va30, ia30, va31, ia31)

        MRG(vc0, ic0, vb0,  ib0,  vb1,  ib1)     MRG(vc1, ic1, vb2,  ib2,  vb3,  ib3)
        MRG(vc2, ic2, vb4,  ib4,  vb5,  ib5)     MRG(vc3, ic3, vb6,  ib6,  vb7,  ib7)
        MRG(vc4, ic4, vb8,  ib8,  vb9,  ib9)     MRG(vc5, ic5, vb10, ib10, vb11, ib11)
        MRG(vc6, ic6, vb12, ib12, vb13, ib13)    MRG(vc7, ic7, vb14, ib14, vb15, ib15)

        MRG(vd0, id0, vc0, ic0, vc1, ic1)        MRG(vd1, id1, vc2, ic2, vc3, ic3)
        MRG(vd2, id2, vc4, ic4, vc5, ic5)        MRG(vd3, id3, vc6, ic6, vc7, ic7)

        MRG(ve0, ie0, vd0, id0, vd1, id1)        MRG(ve1, ie1, vd2, id2, vd3, id3)

        MRG(vf0, if0, ve0, ie0, ve1, ie1)

        bt[(t - 1) * NTAG + c] = (unsigned char)if0;  // fire-and-forget ds_write
        a = vf0 + emit;                               // alpha update in-register
    }

    // final scores: alpha + T[:,EOS]
    float fin = a + trans[c * NTAG + EOS_T];

    // wave argmax: value desc, index asc (first occurrence)
    float v = fin; int idx = c;
    #pragma unroll
    for (int off = 1; off < 64; off <<= 1) {
        float ov = __shfl_xor(v, off, 64);
        int   oi = __shfl_xor(idx, off, 64);
        if (ov > v || (ov == v && oi < idx)) { v = ov; idx = oi; }
    }
    int cur = idx;                                  // best_last (wave-uniform)

    int* orow = out + (size_t)b * SLEN;
    for (int t = len + c; t < SLEN; t += 64) orow[t] = 0;   // PAD tail
    if (c == 0) orow[len - 1] = cur;

    // drain bt ds_writes once, then chase backpointers (uniform -> broadcast)
    asm volatile("s_waitcnt lgkmcnt(0)" ::: "memory");
    for (int t = len - 2; t >= 0; --t) {
        cur = bt[t * NTAG + cur];
        if (c == 0) orow[t] = cur;
    }
}

extern "C" void kernel_launch(void* const* d_in, const int* in_sizes, int n_in,
                              void* d_out, int out_size, void* d_ws, size_t ws_size,
                              hipStream_t stream) {
    const float* emissions = (const float*)d_in[0];
    const float* mask      = (const float*)d_in[1];
    const float* trans     = (const float*)d_in[2];
    int* out = (int*)d_out;

    (void)hipFuncSetAttribute((const void*)crf_viterbi,
                              hipFuncAttributeMaxDynamicSharedMemorySize,
                              LDS_BYTES);

    crf_viterbi<<<NBATCH, 64, LDS_BYTES, stream>>>(emissions, mask, trans, out);
}

// Round 8
// 1119.830 us; speedup vs baseline: 1.8557x; 1.1762x over previous
//
#include <hip/hip_runtime.h>

#define NBATCH 256
#define SLEN   2048
#define NTAG   64
#define BOS_T  1
#define EOS_T  2

// bt: 2047 x 64 B = 131008 -> 131072 ; pv: 2 bufs x 4 waves x 64 x 8B = 4096
#define BT_BYTES 131072
#define PV_BYTES 4096
#define LDS_BYTES (BT_BYTES + PV_BYTES)

// broadcast lane `lane`'s value of v to all lanes (uniform lane -> v_readlane)
__device__ __forceinline__ float lane_bcast(float v, int lane) {
    return __uint_as_float(__builtin_amdgcn_readlane(__float_as_uint(v), lane));
}

#define K16(X) X(0) X(1) X(2) X(3) X(4) X(5) X(6) X(7) \
               X(8) X(9) X(10) X(11) X(12) X(13) X(14) X(15)

#define DECL_TC(k) float tcv##k = trans[(pbase + k) * NTAG + c];
#define KEEP_TC(k) asm volatile("" : "+v"(tcv##k));

// leaf over this wave's prevs; ka<kb; >= keeps lower index on ties
#define LEAF(i, ka, kb) \
  float va##i; int ia##i; { \
    float ca_ = lane_bcast(a, pbase + ka) + tcv##ka; \
    float cb_ = lane_bcast(a, pbase + kb) + tcv##kb; \
    bool g_ = (ca_ >= cb_); \
    va##i = g_ ? ca_ : cb_; ia##i = g_ ? (pbase + ka) : (pbase + kb); }

// merge node: A holds lower indices; >= keeps A on ties
#define MRG(vo, io, vA, iA, vB, iB) \
  float vo; int io; { bool g_ = ((vA) >= (vB)); \
    vo = g_ ? (vA) : (vB); io = g_ ? (iA) : (iB); }

// 4 waves: prev-range split of the max-plus reduction; LDS combine once/step.
// waves_per_eu(1,1): 131KB LDS forces 1 wg/CU at runtime (4 waves = 1/EU);
// compiler can't see extern-shared size, so state it for full VGPR budget.
__global__ __launch_bounds__(256)
__attribute__((amdgpu_waves_per_eu(1, 1)))
void crf_viterbi(const float* __restrict__ emissions,  // [B,S,C]
                 const float* __restrict__ mask,       // [B,S]
                 const float* __restrict__ trans,      // [C,C]
                 int* __restrict__ out)                // [B,S] int32 tags
{
    extern __shared__ unsigned char lds[];
    unsigned char* bt = lds;                    // [S-1][64] backpointers
    uint2* pv = (uint2*)(lds + BT_BYTES);       // [2][4][64] {val,idx}

    const int b   = blockIdx.x;
    const int tid = threadIdx.x;
    const int w   = tid >> 6;                   // wave id 0..3
    const int c   = tid & 63;                   // current tag
    const int pbase = w << 4;                   // this wave's prev range base

    // 16 T-column entries for this wave's prev range (tiny register footprint)
    K16(DECL_TC)

    // length = sum(mask[b,:]) (all waves redundantly; identical result)
    const float* mrow = mask + (size_t)b * SLEN;
    float msum = 0.f;
    #pragma unroll
    for (int k = 0; k < SLEN / 64; ++k) msum += mrow[c + k * 64];
    #pragma unroll
    for (int off = 32; off >= 1; off >>= 1) msum += __shfl_xor(msum, off, 64);
    const int len = (int)msum;                  // in [1024, 2048]

    const float* E = emissions + (size_t)b * SLEN * NTAG;

    // alpha replica in lane registers; identical in all 4 waves
    float a = E[c] + trans[BOS_T * NTAG + c];

    // depth-3 emissions prefetch; raw barrier below never drains vmcnt,
    // so these stay in flight across iterations
    float e0 = E[NTAG + c];
    float e1 = E[((2 < len) ? 2 : (len - 1)) * NTAG + c];
    float e2 = E[((3 < len) ? 3 : (len - 1)) * NTAG + c];

    for (int t = 1; t < len; ++t) {
        K16(KEEP_TC)                            // pin tc in VGPRs (no remat)

        float emit = e0; e0 = e1; e1 = e2;
        int tn = (t + 3 < len) ? (t + 3) : (len - 1);
        e2 = E[tn * NTAG + c];

        // 16-candidate tournament over this wave's prevs (exact first-occurrence)
        LEAF(0, 0, 1)   LEAF(1, 2, 3)   LEAF(2, 4, 5)   LEAF(3, 6, 7)
        LEAF(4, 8, 9)   LEAF(5, 10, 11) LEAF(6, 12, 13) LEAF(7, 14, 15)
        MRG(vb0, ib0, va0, ia0, va1, ia1)  MRG(vb1, ib1, va2, ia2, va3, ia3)
        MRG(vb2, ib2, va4, ia4, va5, ia5)  MRG(vb3, ib3, va6, ia6, va7, ia7)
        MRG(vc0, ic0, vb0, ib0, vb1, ib1)  MRG(vc1, ic1, vb2, ib2, vb3, ib3)
        MRG(vw, iw, vc0, ic0, vc1, ic1)

        // publish partial (double-buffered -> single barrier per step is safe:
        // reads of buf X precede barrier arrival; next write to X is after it)
        uint2* pvbuf = pv + ((t & 1) << 8);
        uint2 mine; mine.x = __float_as_uint(vw); mine.y = (unsigned)iw;
        pvbuf[(w << 6) + c] = mine;

        // drain own LDS write, raw barrier (NO vmcnt drain), compiler fence
        asm volatile("s_waitcnt lgkmcnt(0)\n\ts_barrier" ::: "memory");

        // merge 4 partials in ascending wave order (left bias = lower prevs)
        uint2 q0 = pvbuf[c];
        uint2 q1 = pvbuf[64 + c];
        uint2 q2 = pvbuf[128 + c];
        uint2 q3 = pvbuf[192 + c];
        float f0 = __uint_as_float(q0.x); int j0 = (int)q0.y;
        float f1 = __uint_as_float(q1.x); int j1 = (int)q1.y;
        float f2 = __uint_as_float(q2.x); int j2 = (int)q2.y;
        float f3 = __uint_as_float(q3.x); int j3 = (int)q3.y;
        MRG(m0, n0, f0, j0, f1, j1)
        MRG(m1, n1, f2, j2, f3, j3)
        MRG(m2, n2, m0, n0, m1, n1)

        a = m2 + emit;                          // identical in all waves
        if (w == 0) bt[(t - 1) * NTAG + c] = (unsigned char)n2;
    }

    // final scores: alpha + T[:,EOS]
    float fin = a + trans[c * NTAG + EOS_T];

    // wave argmax: value desc, index asc (first occurrence); same in all waves
    float v = fin; int idx = c;
    #pragma unroll
    for (int off = 1; off < 64; off <<= 1) {
        float ov = __shfl_xor(v, off, 64);
        int   oi = __shfl_xor(idx, off, 64);
        if (ov > v || (ov == v && oi < idx)) { v = ov; idx = oi; }
    }
    int cur = idx;                              // best_last (uniform)

    int* orow = out + (size_t)b * SLEN;
    for (int t = len + tid; t < SLEN; t += 256) orow[t] = 0;   // PAD tail

    if (w != 0) return;                         // no barriers remain
    if (c == 0) orow[len - 1] = cur;

    // drain wave0's bt writes, then chase backpointers (uniform broadcast reads)
    asm volatile("s_waitcnt lgkmcnt(0)" ::: "memory");
    for (int t = len - 2; t >= 0; --t) {
        cur = bt[t * NTAG + cur];
        if (c == 0) orow[t] = cur;
    }
}

extern "C" void kernel_launch(void* const* d_in, const int* in_sizes, int n_in,
                              void* d_out, int out_size, void* d_ws, size_t ws_size,
                              hipStream_t stream) {
    const float* emissions = (const float*)d_in[0];
    const float* mask      = (const float*)d_in[1];
    const float* trans     = (const float*)d_in[2];
    int* out = (int*)d_out;

    (void)hipFuncSetAttribute((const void*)crf_viterbi,
                              hipFuncAttributeMaxDynamicSharedMemorySize,
                              LDS_BYTES);

    crf_viterbi<<<NBATCH, 256, LDS_BYTES, stream>>>(emissions, mask, trans, out);
}